// Round 10
// baseline (18994.873 us; speedup 1.0000x reference)
//
#include <hip/hip_runtime.h>

#define B_SZ 512
#define SEQ 96
#define PRED 48
#define TOT 144
#define CIN 7
#define DM 128
#define GDIM 384
#define KS 5

#define CSTR 132              // LDS row stride for activation buffers
#define ASUB (20*CSTR)        // floats per 20-row sub-buffer
#define WROW 136              // swizzled LDS weight row (128 + pad)
#define SWZ(o) ((o) + ((((o) >> 6)) << 2))   // bank swizzle: pad 4 every 64 floats

#define W_CONV (KS*DM*DM)            // 81920 per conv layer (layout [k][c][o])
#define OFF_WIT (3*W_CONV)           // WiT [c][384]
#define OFF_WHT (3*W_CONV + DM*GDIM) // WhT [c][384]
#define W_TOTAL (3*W_CONV + 2*DM*GDIM)

// Device-global scratch
__device__ float g_gxg[(size_t)B_SZ*TOT*GDIM];  // invariant gx cache, [b][p][384]
__device__ float g_wT[W_TOTAL];                 // transposed weights

// ---------------------------------------------------------------- prep
__global__ void prep_weights(const float* __restrict__ w1, const float* __restrict__ w2,
                             const float* __restrict__ w3, const float* __restrict__ Wi,
                             const float* __restrict__ Wh) {
    int tid = blockIdx.x*256 + threadIdx.x;
    if (tid < 3*W_CONV) {
        int l = tid / W_CONV, r = tid % W_CONV;
        int o = r & 127, c = (r >> 7) & 127, k = r >> 14;   // r = (k*128+c)*128+o
        const float* w = (l==0) ? w1 : ((l==1) ? w2 : w3);
        g_wT[tid] = w[o*(DM*KS) + c*KS + k];                 // src [o][c][k]
    } else if (tid < W_TOTAL) {
        int r = tid - 3*W_CONV;
        int m = r / (DM*GDIM), q = r % (DM*GDIM);
        int g = q % GDIM, c = q / GDIM;                      // dst [c][g]
        const float* W = (m==0) ? Wi : Wh;
        g_wT[tid] = W[g*DM + c];                             // src [g][c]
    }
}

// ---------------------------------------------------------------- fma helper
template<int NJ>
__device__ __forceinline__ void fma8(float (&acc)[NJ][8], int j, float a,
                                     const float4& wA, const float4& wB) {
    acc[j][0] = fmaf(a, wA.x, acc[j][0]);
    acc[j][1] = fmaf(a, wA.y, acc[j][1]);
    acc[j][2] = fmaf(a, wA.z, acc[j][2]);
    acc[j][3] = fmaf(a, wA.w, acc[j][3]);
    acc[j][4] = fmaf(a, wB.x, acc[j][4]);
    acc[j][5] = fmaf(a, wB.y, acc[j][5]);
    acc[j][6] = fmaf(a, wB.z, acc[j][6]);
    acc[j][7] = fmaf(a, wB.w, acc[j][7]);
}

// stage 8 channels of conv weights (swizzled) into wbuf — 256-thread version (init)
__device__ __forceinline__ void stage_conv_chunk(float* __restrict__ wbuf,
                                                 const float* __restrict__ wT,
                                                 int cc, int tid) {
    const int cj = tid >> 5, oo = (tid & 31) * 4;
    #pragma unroll
    for (int k = 0; k < KS; ++k)
        *(float4*)(wbuf + (k*8 + cj)*WROW + SWZ(oo)) =
            *(const float4*)(wT + (k*DM + cc*8 + cj)*DM + oo);
}

// Chunked in-place conv layer (init kernel, 256 threads).
template<int NJ>
__device__ __forceinline__ void conv_layer_chunked(float* __restrict__ buf,
                                                   float* __restrict__ wbuf,
                                                   const float* __restrict__ wT,
                                                   const float* __restrict__ bias,
                                                   int nrow, int winO, int tid) {
    const int og = tid & 15, ttg = tid >> 4;
    const int o0 = og*8, so0 = SWZ(o0), r0 = ttg*NJ;
    const bool act = (r0 < nrow);
    float acc[NJ][8];
    #pragma unroll
    for (int u = 0; u < 8; ++u) {
        float bv = bias[o0+u];
        #pragma unroll
        for (int j = 0; j < NJ; ++j) acc[j][u] = bv;
    }
    for (int cc = 0; cc < DM/8; ++cc) {
        __syncthreads();
        stage_conv_chunk(wbuf, wT, cc, tid);
        __syncthreads();
        if (act) {
            const int c0 = cc*8;
            #pragma unroll
            for (int cj = 0; cj < 8; cj += 2) {
                float2 a2[NJ+4];
                #pragma unroll
                for (int m = 0; m < NJ+4; ++m)
                    a2[m] = *(const float2*)(buf + (r0+m)*CSTR + c0 + cj);
                #pragma unroll
                for (int k = 0; k < KS; ++k) {
                    const float4 wA0 = *(const float4*)(wbuf + (k*8+cj)*WROW + so0);
                    const float4 wB0 = *(const float4*)(wbuf + (k*8+cj)*WROW + so0 + 4);
                    const float4 wA1 = *(const float4*)(wbuf + (k*8+cj+1)*WROW + so0);
                    const float4 wB1 = *(const float4*)(wbuf + (k*8+cj+1)*WROW + so0 + 4);
                    #pragma unroll
                    for (int j = 0; j < NJ; ++j) {
                        fma8(acc, j, a2[j+k].x, wA0, wB0);
                        fma8(acc, j, a2[j+k].y, wA1, wB1);
                    }
                }
            }
        }
    }
    __syncthreads();
    if (act) {
        #pragma unroll
        for (int j = 0; j < NJ; ++j) {
            int q = r0 + j, w = winO + q;
            bool valid = (w >= 0) && (w < SEQ);
            #pragma unroll
            for (int u = 0; u < 8; ++u)
                buf[q*CSTR + o0+u] = valid ? fmaxf(acc[j][u], 0.f) : 0.f;
        }
    }
    __syncthreads();
}

// ------------------------------------------------------------- init kernel
// Step 0's full conv cascade; stores invariant gx rows w in [6,90) to g_gxg[b][w].
__launch_bounds__(256, 3)
__global__ void init_kernel(const float* __restrict__ x_enc,
                            const int* __restrict__ y_mark,
                            const float* __restrict__ hour_e, const float* __restrict__ wk_e,
                            const float* __restrict__ day_e, const float* __restrict__ mon_e,
                            const float* __restrict__ W_val, const float* __restrict__ b_val,
                            const float* __restrict__ b1, const float* __restrict__ b2,
                            const float* __restrict__ b3, const float* __restrict__ gbi) {
    __shared__ float buf[60*CSTR];
    __shared__ float wbuf[KS*8*WROW];
    const int tid = threadIdx.x;
    const int b = blockIdx.x;
    const int cs = blockIdx.y * 48;

    for (int e = tid; e < 60*DM; e += 256) {
        int q = e >> 7, d = e & 127;
        int w = cs - 6 + q;
        float v = 0.f;
        if (w >= 0 && w < SEQ) {
            const float* xr = x_enc + (b*SEQ + w)*CIN;
            v = b_val[d];
            #pragma unroll
            for (int c = 0; c < CIN; ++c) v = fmaf(xr[c], W_val[d*CIN + c], v);
            const int* ym = y_mark + (b*TOT + w)*4;
            v += hour_e[ym[0]*DM + d] + wk_e[ym[1]*DM + d]
               + day_e[ym[2]*DM + d] + mon_e[ym[3]*DM + d];
        }
        buf[q*CSTR + d] = v;
    }
    conv_layer_chunked<4>(buf, wbuf, g_wT,            b1, 56, cs - 4, tid);
    conv_layer_chunked<4>(buf, wbuf, g_wT + W_CONV,   b2, 52, cs - 2, tid);
    conv_layer_chunked<3>(buf, wbuf, g_wT + 2*W_CONV, b3, 48, cs,     tid);

    const int og = tid & 15, ttg = tid >> 4;
    const int g0 = og*24, r0 = ttg*3;
    const float* WiT = g_wT + OFF_WIT;
    float ga[3][24];
    #pragma unroll
    for (int e = 0; e < 24; ++e) {
        float bv = gbi[g0+e];
        #pragma unroll
        for (int j = 0; j < 3; ++j) ga[j][e] = bv;
    }
    for (int cc = 0; cc < DM/8; ++cc) {
        __syncthreads();
        #pragma unroll
        for (int s = 0; s < 3; ++s)
            ((float4*)wbuf)[s*256 + tid] = ((const float4*)(WiT + cc*8*GDIM))[s*256 + tid];
        __syncthreads();
        const int c0 = cc*8;
        #pragma unroll
        for (int cj = 0; cj < 8; cj += 2) {
            float2 a2[3];
            #pragma unroll
            for (int m = 0; m < 3; ++m)
                a2[m] = *(const float2*)(buf + (r0+m)*CSTR + c0 + cj);
            float4 w4[6];
            #pragma unroll
            for (int q = 0; q < 6; ++q)
                w4[q] = *(const float4*)(wbuf + cj*GDIM + g0 + q*4);
            const float* wv = (const float*)w4;
            #pragma unroll
            for (int j = 0; j < 3; ++j)
                #pragma unroll
                for (int e = 0; e < 24; ++e)
                    ga[j][e] = fmaf(a2[j].x, wv[e], ga[j][e]);
            #pragma unroll
            for (int q = 0; q < 6; ++q)
                w4[q] = *(const float4*)(wbuf + (cj+1)*GDIM + g0 + q*4);
            #pragma unroll
            for (int j = 0; j < 3; ++j)
                #pragma unroll
                for (int e = 0; e < 24; ++e)
                    ga[j][e] = fmaf(a2[j].y, wv[e], ga[j][e]);
        }
    }
    #pragma unroll
    for (int j = 0; j < 3; ++j) {
        int w = cs + r0 + j;
        if (w >= 6 && w < 90) {
            float* gxo = g_gxg + ((size_t)b*TOT + w)*GDIM + g0;
            #pragma unroll
            for (int q = 0; q < 6; ++q)
                *(float4*)(gxo + q*4) = *(const float4*)&ga[j][q*4];
        }
    }
}

// ------------------------------------------------------------- fused layer
// 512 threads, 2 sub-buffers (left/right edge of one batch). R rows/sub, 1 row/thread.
__device__ __forceinline__ void flayer(float* __restrict__ abuf, float* __restrict__ wbuf,
                                       const float* __restrict__ wT,
                                       const float* __restrict__ bias,
                                       int R, int off, int tid) {
    const int og = tid & 15, ttg = tid >> 4;     // og 0..15, ttg 0..31
    const int o0 = og*8, so0 = SWZ(o0);
    const bool act = (ttg < 2*R);
    int s = 0, r0 = 0;
    if (act) { s = ttg / R; r0 = ttg - s*R; }
    float* in = abuf + s*ASUB;
    float acc[8];
    #pragma unroll
    for (int u = 0; u < 8; ++u) acc[u] = bias[o0+u];
    for (int cc = 0; cc < DM/8; ++cc) {
        __syncthreads();
        for (int x = tid; x < 1280; x += 512) {   // 5 k x 8 c x 32 float4
            int k = x >> 8, rr = (x >> 5) & 7, oo = (x & 31)*4;
            *(float4*)(wbuf + (k*8+rr)*WROW + SWZ(oo)) =
                *(const float4*)(wT + (k*DM + cc*8 + rr)*DM + oo);
        }
        __syncthreads();
        if (act) {
            const int c0 = cc*8;
            #pragma unroll
            for (int cj = 0; cj < 8; cj += 2) {
                float2 a2[5];
                #pragma unroll
                for (int m = 0; m < 5; ++m)
                    a2[m] = *(const float2*)(in + (r0+m)*CSTR + c0 + cj);
                #pragma unroll
                for (int k = 0; k < KS; ++k) {
                    const float4 wA0 = *(const float4*)(wbuf + (k*8+cj)*WROW + so0);
                    const float4 wB0 = *(const float4*)(wbuf + (k*8+cj)*WROW + so0 + 4);
                    const float4 wA1 = *(const float4*)(wbuf + (k*8+cj+1)*WROW + so0);
                    const float4 wB1 = *(const float4*)(wbuf + (k*8+cj+1)*WROW + so0 + 4);
                    acc[0] = fmaf(a2[k].x, wA0.x, acc[0]); acc[1] = fmaf(a2[k].x, wA0.y, acc[1]);
                    acc[2] = fmaf(a2[k].x, wA0.z, acc[2]); acc[3] = fmaf(a2[k].x, wA0.w, acc[3]);
                    acc[4] = fmaf(a2[k].x, wB0.x, acc[4]); acc[5] = fmaf(a2[k].x, wB0.y, acc[5]);
                    acc[6] = fmaf(a2[k].x, wB0.z, acc[6]); acc[7] = fmaf(a2[k].x, wB0.w, acc[7]);
                    acc[0] = fmaf(a2[k].y, wA1.x, acc[0]); acc[1] = fmaf(a2[k].y, wA1.y, acc[1]);
                    acc[2] = fmaf(a2[k].y, wA1.z, acc[2]); acc[3] = fmaf(a2[k].y, wA1.w, acc[3]);
                    acc[4] = fmaf(a2[k].y, wB1.x, acc[4]); acc[5] = fmaf(a2[k].y, wB1.y, acc[5]);
                    acc[6] = fmaf(a2[k].y, wB1.z, acc[6]); acc[7] = fmaf(a2[k].y, wB1.w, acc[7]);
                }
            }
        }
    }
    __syncthreads();
    if (act) {
        const int wb = s ? 83 : -6;
        int w = wb + off + r0;
        bool valid = (w >= 0) && (w < SEQ);
        #pragma unroll
        for (int u = 0; u < 8; ++u)
            in[r0*CSTR + o0+u] = valid ? fmaxf(acc[u], 0.f) : 0.f;
    }
    __syncthreads();
}

// ------------------------------------------------------------- fused step+GRU
// grid 512 (one batch/block), 512 threads. Phases: edge embedding -> 3 convs ->
// gx (edges -> LDS gxe, invariant w=89 -> g_gxg) -> slice-GRU (96 t) -> FC.
// __launch_bounds__(512, 2): min 2 waves/EU -> 256-VGPR cap. WITHOUT the second
// arg the heuristic picked 84 VGPRs and spilled the wh[32]x3 slices to scratch
// (round 9: FETCH 93 MB/dispatch, 380 us/step). The bound IS the fix.
__launch_bounds__(512, 2)
__global__ void step_gru(int i, const float* __restrict__ x_enc,
                         const int* __restrict__ y_mark,
                         const float* __restrict__ hour_e, const float* __restrict__ wk_e,
                         const float* __restrict__ day_e, const float* __restrict__ mon_e,
                         const float* __restrict__ W_val, const float* __restrict__ b_val,
                         const float* __restrict__ b1, const float* __restrict__ b2,
                         const float* __restrict__ b3, const float* __restrict__ gbi,
                         const float* __restrict__ gbh, const float* __restrict__ fc_w,
                         const float* __restrict__ fc_b, float* __restrict__ out) {
    __shared__ float abuf[2*ASUB];     // 21,120 B: sub0 left (wbase -6), sub1 right (wbase 83)
    __shared__ float wbuf[16*GDIM];    // 24,576 B: conv/WiT chunks; later P + H
    __shared__ float gxe[12*GDIM];     // 18,432 B: edge gx rows (t<6 -> 0..5, t>=90 -> 6..11)
    const int tid = threadIdx.x;
    const int b = blockIdx.x;

    // ---- phase 1: embedding, 2 subs x 20 rows
    for (int e = tid; e < 2*20*DM; e += 512) {
        int s = e / (20*DM);
        int rem = e - s*(20*DM);
        int q = rem >> 7, d = rem & 127;
        int wb = s ? 83 : -6;
        int w = wb + q;
        float v = 0.f;
        if (w >= 0 && w < SEQ) {
            int p = i + w;
            const float* xr = (p < SEQ) ? (x_enc + (b*SEQ + p)*CIN)
                                        : (out + (b*PRED + (p - SEQ))*CIN);
            v = b_val[d];
            #pragma unroll
            for (int c = 0; c < CIN; ++c) v = fmaf(xr[c], W_val[d*CIN + c], v);
            const int* ym = y_mark + (b*TOT + p)*4;
            v += hour_e[ym[0]*DM + d] + wk_e[ym[1]*DM + d]
               + day_e[ym[2]*DM + d] + mon_e[ym[3]*DM + d];
        }
        abuf[s*ASUB + q*CSTR + d] = v;
    }
    // ---- phase 2: conv cascade (flayer starts with __syncthreads)
    flayer(abuf, wbuf, g_wT,            b1, 16, 2, tid);  // c1: 2x16 rows
    flayer(abuf, wbuf, g_wT + W_CONV,   b2, 12, 4, tid);  // c2: 2x12 rows
    flayer(abuf, wbuf, g_wT + 2*W_CONV, b3,  8, 6, tid);  // c3: 2x8 rows (at q 0..7)

    // ---- phase 3: gx for 16 c3 rows; thread = (row m = tid>>5, 12 g's)
    {
        const int m = tid >> 5;              // 0..15
        const int g0 = (tid & 31) * 12;
        const int s = m >> 3, row = m & 7;
        const float* ap = abuf + s*ASUB + row*CSTR;
        const float* WiT = g_wT + OFF_WIT;
        float ga[12];
        #pragma unroll
        for (int e = 0; e < 12; ++e) ga[e] = gbi[g0+e];
        for (int cc = 0; cc < 8; ++cc) {
            __syncthreads();
            for (int x = tid; x < 16*GDIM/4; x += 512)
                ((float4*)wbuf)[x] = ((const float4*)(WiT + cc*16*GDIM))[x];
            __syncthreads();
            #pragma unroll
            for (int c = 0; c < 16; ++c) {
                float a = ap[cc*16 + c];
                const float* wr = wbuf + c*GDIM + g0;
                #pragma unroll
                for (int q4 = 0; q4 < 3; ++q4) {
                    float4 w4 = *(const float4*)(wr + q4*4);
                    ga[q4*4+0] = fmaf(a, w4.x, ga[q4*4+0]);
                    ga[q4*4+1] = fmaf(a, w4.y, ga[q4*4+1]);
                    ga[q4*4+2] = fmaf(a, w4.z, ga[q4*4+2]);
                    ga[q4*4+3] = fmaf(a, w4.w, ga[q4*4+3]);
                }
            }
        }
        const int w = (s ? 83 : -6) + 6 + row;
        float* dst = nullptr;
        if (s == 0) {
            if (w < 6) dst = gxe + w*GDIM + g0;                           // t<6 rows
        } else {
            if (w == 89)      dst = g_gxg + ((size_t)b*TOT + (i + 89))*GDIM + g0;
            else if (w < SEQ) dst = gxe + (w - 84)*GDIM + g0;             // t>=90 rows
        }
        if (dst) {
            *(float4*)(dst)     = *(const float4*)&ga[0];
            *(float4*)(dst + 4) = *(const float4*)&ga[4];
            *(float4*)(dst + 8) = *(const float4*)&ga[8];
        }
    }
    __syncthreads();   // gxe + g_gxg(w=89) visible; wbuf free for P/H

    // ---- phase 4: GRU. thread = (unit j, c-slice s). wh slices loaded here
    // (not earlier) so conv-phase register pressure stays low.
    float* P = wbuf;              // [3][4][DM] partials
    float* H = wbuf + 3*4*DM;     // [2][DM] ping-pong hidden state
    const int j = tid & 127, s4 = tid >> 7;
    float whr[32], whz[32], whn[32];
    {
        const float* Wp = g_wT + OFF_WHT + (size_t)(32*s4)*GDIM + j;
        #pragma unroll
        for (int c = 0; c < 32; ++c) {
            whr[c] = Wp[c*GDIM];
            whz[c] = Wp[c*GDIM + DM];
            whn[c] = Wp[c*GDIM + 2*DM];
        }
    }
    const bool comb = (tid < DM);
    const float* gxg_b = g_gxg + (size_t)b*TOT*GDIM;
    float bhr = 0.f, bhz = 0.f, bhn = 0.f, h = 0.f;
    float gxr = 0.f, gxz = 0.f, gxn = 0.f;
    if (comb) {
        bhr = gbh[j]; bhz = gbh[DM + j]; bhn = gbh[2*DM + j];
        H[j] = 0.f;                       // H[0][j]
        gxr = gxe[j]; gxz = gxe[DM + j]; gxn = gxe[2*DM + j];   // t = 0
    }
    __syncthreads();

    for (int t = 0; t < SEQ; ++t) {
        const float* Hc = H + (t & 1)*DM + 32*s4;   // wave-uniform -> broadcast
        float ar = 0.f, az = 0.f, an = 0.f;
        #pragma unroll
        for (int c = 0; c < 32; c += 4) {
            float4 h4 = *(const float4*)(Hc + c);
            ar = fmaf(h4.x, whr[c],   ar); az = fmaf(h4.x, whz[c],   az); an = fmaf(h4.x, whn[c],   an);
            ar = fmaf(h4.y, whr[c+1], ar); az = fmaf(h4.y, whz[c+1], az); an = fmaf(h4.y, whn[c+1], an);
            ar = fmaf(h4.z, whr[c+2], ar); az = fmaf(h4.z, whz[c+2], az); an = fmaf(h4.z, whn[c+2], an);
            ar = fmaf(h4.w, whr[c+3], ar); az = fmaf(h4.w, whz[c+3], az); an = fmaf(h4.w, whn[c+3], an);
        }
        P[(0*4 + s4)*DM + j] = ar;
        P[(1*4 + s4)*DM + j] = az;
        P[(2*4 + s4)*DM + j] = an;
        __syncthreads();
        if (comb) {
            float ar2 = bhr + ((P[0*DM + j] + P[1*DM + j]) + (P[2*DM + j] + P[3*DM + j]));
            float az2 = bhz + ((P[4*DM + j] + P[5*DM + j]) + (P[6*DM + j] + P[7*DM + j]));
            float an2 = bhn + ((P[8*DM + j] + P[9*DM + j]) + (P[10*DM + j] + P[11*DM + j]));
            float r = 1.f/(1.f + __expf(-(gxr + ar2)));
            float z = 1.f/(1.f + __expf(-(gxz + az2)));
            float xn = gxn + r*an2;
            float e2 = __expf(2.f*xn);
            float n = 1.f - 2.f/(e2 + 1.f);           // tanh(xn)
            h = (1.f - z)*n + z*h;
            H[((t + 1) & 1)*DM + j] = h;
            if (t + 1 < SEQ) {                        // prefetch next t's gx
                int t1 = t + 1;
                const float* gq = (t1 < 6)  ? (gxe + t1*GDIM)
                                : (t1 < 90) ? (gxg_b + (size_t)(i + t1)*GDIM)
                                            : (gxe + (t1 - 84)*GDIM);
                gxr = gq[j]; gxz = gq[DM + j]; gxn = gq[2*DM + j];
            }
        }
        __syncthreads();
    }

    // ---- FC: pred = h @ fc_w^T + fc_b (SEQ even -> final state at H[0])
    if (tid < CIN) {
        float p = fc_b[tid];
        #pragma unroll
        for (int d = 0; d < DM; ++d) p = fmaf(fc_w[tid*DM + d], H[d], p);
        out[(b*PRED + i)*CIN + tid] = p;
    }
}

// ---------------------------------------------------------------- launch
extern "C" void kernel_launch(void* const* d_in, const int* in_sizes, int n_in,
                              void* d_out, int out_size, void* d_ws, size_t ws_size,
                              hipStream_t stream) {
    const float* x_enc  = (const float*)d_in[0];
    const int*   y_mark = (const int*)d_in[2];
    const float* hour_e = (const float*)d_in[3];
    const float* wk_e   = (const float*)d_in[4];
    const float* day_e  = (const float*)d_in[5];
    const float* mon_e  = (const float*)d_in[6];
    const float* W_val  = (const float*)d_in[7];
    const float* b_val  = (const float*)d_in[8];
    const float* c1w    = (const float*)d_in[9];
    const float* c1b    = (const float*)d_in[10];
    const float* c2w    = (const float*)d_in[11];
    const float* c2b    = (const float*)d_in[12];
    const float* c3w    = (const float*)d_in[13];
    const float* c3b    = (const float*)d_in[14];
    const float* Wi     = (const float*)d_in[15];
    const float* Wh     = (const float*)d_in[16];
    const float* gbi    = (const float*)d_in[17];
    const float* gbh    = (const float*)d_in[18];
    const float* fcw    = (const float*)d_in[19];
    const float* fcb    = (const float*)d_in[20];
    float* out = (float*)d_out;

    prep_weights<<<(W_TOTAL + 255)/256, 256, 0, stream>>>(c1w, c2w, c3w, Wi, Wh);

    init_kernel<<<dim3(B_SZ, 2), 256, 0, stream>>>(x_enc, y_mark,
        hour_e, wk_e, day_e, mon_e, W_val, b_val, c1b, c2b, c3b, gbi);

    for (int i = 0; i < PRED; ++i) {
        step_gru<<<B_SZ, 512, 0, stream>>>(i, x_enc, y_mark,
            hour_e, wk_e, day_e, mon_e, W_val, b_val, c1b, c2b, c3b,
            gbi, gbh, fcw, fcb, out);
    }
}

// Round 11
// 12401.537 us; speedup vs baseline: 1.5317x; 1.5317x over previous
//
#include <hip/hip_runtime.h>

#define B_SZ 512
#define SEQ 96
#define PRED 48
#define TOT 144
#define CIN 7
#define DM 128
#define GDIM 384
#define KS 5

#define CSTR 132              // LDS row stride for activation buffers
#define ASUB (20*CSTR)        // floats per 20-row sub-buffer
#define WROW 136              // swizzled LDS weight row (128 + pad)
#define SWZ(o) ((o) + ((((o) >> 6)) << 2))   // bank swizzle: pad 4 every 64 floats

#define W_CONV (KS*DM*DM)            // 81920 per conv layer (layout [k][c][o])
#define OFF_WIT (3*W_CONV)           // WiT [c][384]
#define OFF_WHT (3*W_CONV + DM*GDIM) // WhT [c][384]
#define W_TOTAL (3*W_CONV + 2*DM*GDIM)

#define NBB 2                 // batches per fused block

// Device-global scratch
__device__ float g_gxg[(size_t)B_SZ*TOT*GDIM];  // invariant gx cache, [b][p][384]
__device__ float g_wT[W_TOTAL];                 // transposed weights

// ---------------------------------------------------------------- prep
__global__ void prep_weights(const float* __restrict__ w1, const float* __restrict__ w2,
                             const float* __restrict__ w3, const float* __restrict__ Wi,
                             const float* __restrict__ Wh) {
    int tid = blockIdx.x*256 + threadIdx.x;
    if (tid < 3*W_CONV) {
        int l = tid / W_CONV, r = tid % W_CONV;
        int o = r & 127, c = (r >> 7) & 127, k = r >> 14;   // r = (k*128+c)*128+o
        const float* w = (l==0) ? w1 : ((l==1) ? w2 : w3);
        g_wT[tid] = w[o*(DM*KS) + c*KS + k];                 // src [o][c][k]
    } else if (tid < W_TOTAL) {
        int r = tid - 3*W_CONV;
        int m = r / (DM*GDIM), q = r % (DM*GDIM);
        int g = q % GDIM, c = q / GDIM;                      // dst [c][g]
        const float* W = (m==0) ? Wi : Wh;
        g_wT[tid] = W[g*DM + c];                             // src [g][c]
    }
}

// ---------------------------------------------------------------- fma helper
template<int NJ>
__device__ __forceinline__ void fma8(float (&acc)[NJ][8], int j, float a,
                                     const float4& wA, const float4& wB) {
    acc[j][0] = fmaf(a, wA.x, acc[j][0]);
    acc[j][1] = fmaf(a, wA.y, acc[j][1]);
    acc[j][2] = fmaf(a, wA.z, acc[j][2]);
    acc[j][3] = fmaf(a, wA.w, acc[j][3]);
    acc[j][4] = fmaf(a, wB.x, acc[j][4]);
    acc[j][5] = fmaf(a, wB.y, acc[j][5]);
    acc[j][6] = fmaf(a, wB.z, acc[j][6]);
    acc[j][7] = fmaf(a, wB.w, acc[j][7]);
}

// stage 8 channels of conv weights (swizzled) into wbuf — 256-thread version (init)
__device__ __forceinline__ void stage_conv_chunk(float* __restrict__ wbuf,
                                                 const float* __restrict__ wT,
                                                 int cc, int tid) {
    const int cj = tid >> 5, oo = (tid & 31) * 4;
    #pragma unroll
    for (int k = 0; k < KS; ++k)
        *(float4*)(wbuf + (k*8 + cj)*WROW + SWZ(oo)) =
            *(const float4*)(wT + (k*DM + cc*8 + cj)*DM + oo);
}

// Chunked in-place conv layer (init kernel, 256 threads).
template<int NJ>
__device__ __forceinline__ void conv_layer_chunked(float* __restrict__ buf,
                                                   float* __restrict__ wbuf,
                                                   const float* __restrict__ wT,
                                                   const float* __restrict__ bias,
                                                   int nrow, int winO, int tid) {
    const int og = tid & 15, ttg = tid >> 4;
    const int o0 = og*8, so0 = SWZ(o0), r0 = ttg*NJ;
    const bool act = (r0 < nrow);
    float acc[NJ][8];
    #pragma unroll
    for (int u = 0; u < 8; ++u) {
        float bv = bias[o0+u];
        #pragma unroll
        for (int j = 0; j < NJ; ++j) acc[j][u] = bv;
    }
    for (int cc = 0; cc < DM/8; ++cc) {
        __syncthreads();
        stage_conv_chunk(wbuf, wT, cc, tid);
        __syncthreads();
        if (act) {
            const int c0 = cc*8;
            #pragma unroll
            for (int cj = 0; cj < 8; cj += 2) {
                float2 a2[NJ+4];
                #pragma unroll
                for (int m = 0; m < NJ+4; ++m)
                    a2[m] = *(const float2*)(buf + (r0+m)*CSTR + c0 + cj);
                #pragma unroll
                for (int k = 0; k < KS; ++k) {
                    const float4 wA0 = *(const float4*)(wbuf + (k*8+cj)*WROW + so0);
                    const float4 wB0 = *(const float4*)(wbuf + (k*8+cj)*WROW + so0 + 4);
                    const float4 wA1 = *(const float4*)(wbuf + (k*8+cj+1)*WROW + so0);
                    const float4 wB1 = *(const float4*)(wbuf + (k*8+cj+1)*WROW + so0 + 4);
                    #pragma unroll
                    for (int j = 0; j < NJ; ++j) {
                        fma8(acc, j, a2[j+k].x, wA0, wB0);
                        fma8(acc, j, a2[j+k].y, wA1, wB1);
                    }
                }
            }
        }
    }
    __syncthreads();
    if (act) {
        #pragma unroll
        for (int j = 0; j < NJ; ++j) {
            int q = r0 + j, w = winO + q;
            bool valid = (w >= 0) && (w < SEQ);
            #pragma unroll
            for (int u = 0; u < 8; ++u)
                buf[q*CSTR + o0+u] = valid ? fmaxf(acc[j][u], 0.f) : 0.f;
        }
    }
    __syncthreads();
}

// ------------------------------------------------------------- init kernel
// Step 0's full conv cascade; stores invariant gx rows w in [6,90) to g_gxg[b][w].
__launch_bounds__(256, 3)
__global__ void init_kernel(const float* __restrict__ x_enc,
                            const int* __restrict__ y_mark,
                            const float* __restrict__ hour_e, const float* __restrict__ wk_e,
                            const float* __restrict__ day_e, const float* __restrict__ mon_e,
                            const float* __restrict__ W_val, const float* __restrict__ b_val,
                            const float* __restrict__ b1, const float* __restrict__ b2,
                            const float* __restrict__ b3, const float* __restrict__ gbi) {
    __shared__ float buf[60*CSTR];
    __shared__ float wbuf[KS*8*WROW];
    const int tid = threadIdx.x;
    const int b = blockIdx.x;
    const int cs = blockIdx.y * 48;

    for (int e = tid; e < 60*DM; e += 256) {
        int q = e >> 7, d = e & 127;
        int w = cs - 6 + q;
        float v = 0.f;
        if (w >= 0 && w < SEQ) {
            const float* xr = x_enc + (b*SEQ + w)*CIN;
            v = b_val[d];
            #pragma unroll
            for (int c = 0; c < CIN; ++c) v = fmaf(xr[c], W_val[d*CIN + c], v);
            const int* ym = y_mark + (b*TOT + w)*4;
            v += hour_e[ym[0]*DM + d] + wk_e[ym[1]*DM + d]
               + day_e[ym[2]*DM + d] + mon_e[ym[3]*DM + d];
        }
        buf[q*CSTR + d] = v;
    }
    conv_layer_chunked<4>(buf, wbuf, g_wT,            b1, 56, cs - 4, tid);
    conv_layer_chunked<4>(buf, wbuf, g_wT + W_CONV,   b2, 52, cs - 2, tid);
    conv_layer_chunked<3>(buf, wbuf, g_wT + 2*W_CONV, b3, 48, cs,     tid);

    const int og = tid & 15, ttg = tid >> 4;
    const int g0 = og*24, r0 = ttg*3;
    const float* WiT = g_wT + OFF_WIT;
    float ga[3][24];
    #pragma unroll
    for (int e = 0; e < 24; ++e) {
        float bv = gbi[g0+e];
        #pragma unroll
        for (int j = 0; j < 3; ++j) ga[j][e] = bv;
    }
    for (int cc = 0; cc < DM/8; ++cc) {
        __syncthreads();
        #pragma unroll
        for (int s = 0; s < 3; ++s)
            ((float4*)wbuf)[s*256 + tid] = ((const float4*)(WiT + cc*8*GDIM))[s*256 + tid];
        __syncthreads();
        const int c0 = cc*8;
        #pragma unroll
        for (int cj = 0; cj < 8; cj += 2) {
            float2 a2[3];
            #pragma unroll
            for (int m = 0; m < 3; ++m)
                a2[m] = *(const float2*)(buf + (r0+m)*CSTR + c0 + cj);
            float4 w4[6];
            #pragma unroll
            for (int q = 0; q < 6; ++q)
                w4[q] = *(const float4*)(wbuf + cj*GDIM + g0 + q*4);
            const float* wv = (const float*)w4;
            #pragma unroll
            for (int j = 0; j < 3; ++j)
                #pragma unroll
                for (int e = 0; e < 24; ++e)
                    ga[j][e] = fmaf(a2[j].x, wv[e], ga[j][e]);
            #pragma unroll
            for (int q = 0; q < 6; ++q)
                w4[q] = *(const float4*)(wbuf + (cj+1)*GDIM + g0 + q*4);
            #pragma unroll
            for (int j = 0; j < 3; ++j)
                #pragma unroll
                for (int e = 0; e < 24; ++e)
                    ga[j][e] = fmaf(a2[j].y, wv[e], ga[j][e]);
        }
    }
    #pragma unroll
    for (int j = 0; j < 3; ++j) {
        int w = cs + r0 + j;
        if (w >= 6 && w < 90) {
            float* gxo = g_gxg + ((size_t)b*TOT + w)*GDIM + g0;
            #pragma unroll
            for (int q = 0; q < 6; ++q)
                *(float4*)(gxo + q*4) = *(const float4*)&ga[j][q*4];
        }
    }
}

// ------------------------------------------------------------- merged conv layer
// 512 threads, 4 sub-buffers (2 batches x 2 edges). R rows/sub, NJ rows/thread.
template<int NJ>
__device__ __forceinline__ void mlayer(float* __restrict__ abuf, float* __restrict__ wbuf,
                                       const float* __restrict__ wT,
                                       const float* __restrict__ bias,
                                       int R, int off, int tid) {
    const int og = tid & 15, ttg = tid >> 4;     // og 0..15, ttg 0..31
    const int o0 = og*8, so0 = SWZ(o0);
    const int m0 = ttg * NJ;
    const bool act = (m0 < 4*R);
    int s = 0, r0 = 0;
    if (act) { s = m0 / R; r0 = m0 - s*R; }      // NJ divides R -> rows don't span subs
    float* in = abuf + s*ASUB;
    float acc[NJ][8];
    #pragma unroll
    for (int u = 0; u < 8; ++u) {
        float bv = bias[o0+u];
        #pragma unroll
        for (int j = 0; j < NJ; ++j) acc[j][u] = bv;
    }
    for (int cc = 0; cc < DM/8; ++cc) {
        __syncthreads();
        for (int x = tid; x < 1280; x += 512) {   // 5 k x 8 c x 32 float4
            int k = x >> 8, rr = (x >> 5) & 7, oo = (x & 31)*4;
            *(float4*)(wbuf + (k*8+rr)*WROW + SWZ(oo)) =
                *(const float4*)(wT + (k*DM + cc*8 + rr)*DM + oo);
        }
        __syncthreads();
        if (act) {
            const int c0 = cc*8;
            #pragma unroll
            for (int cj = 0; cj < 8; cj += 2) {
                float2 a2[NJ+4];
                #pragma unroll
                for (int m = 0; m < NJ+4; ++m)
                    a2[m] = *(const float2*)(in + (r0+m)*CSTR + c0 + cj);
                #pragma unroll
                for (int k = 0; k < KS; ++k) {
                    const float4 wA0 = *(const float4*)(wbuf + (k*8+cj)*WROW + so0);
                    const float4 wB0 = *(const float4*)(wbuf + (k*8+cj)*WROW + so0 + 4);
                    const float4 wA1 = *(const float4*)(wbuf + (k*8+cj+1)*WROW + so0);
                    const float4 wB1 = *(const float4*)(wbuf + (k*8+cj+1)*WROW + so0 + 4);
                    #pragma unroll
                    for (int j = 0; j < NJ; ++j) {
                        fma8(acc, j, a2[j+k].x, wA0, wB0);
                        fma8(acc, j, a2[j+k].y, wA1, wB1);
                    }
                }
            }
        }
    }
    __syncthreads();
    if (act) {
        const int wb = (s & 1) ? 83 : -6;
        #pragma unroll
        for (int j = 0; j < NJ; ++j) {
            int q = r0 + j, w = wb + off + q;
            bool valid = (w >= 0) && (w < SEQ);
            #pragma unroll
            for (int u = 0; u < 8; ++u)
                in[q*CSTR + o0+u] = valid ? fmaxf(acc[j][u], 0.f) : 0.f;
        }
    }
    __syncthreads();
}

// ------------------------------------------------------------- fused step+GRU
// grid 256 (NBB=2 batches/block), 512 threads. Phases: embedding -> 3 convs ->
// gx (edge rows -> LDS gxe, invariant w=89 -> g_gxg) -> slice-GRU -> FC.
// amdgpu_waves_per_eu(2,2) pins the occupancy TARGET at 2 waves/EU (256-VGPR
// budget): launch_bounds' min-only form (r10) left the heuristic free to pick
// 84 VGPR and spill the wh slices to scratch (~270 us/step of L2 reloads).
// LDS 103.7 KB > 80 KB also hardware-forces 1 block/CU, matching the pin.
__global__ __attribute__((amdgpu_waves_per_eu(2, 2)))
__launch_bounds__(512)
void step_gru(int i, const float* __restrict__ x_enc,
              const int* __restrict__ y_mark,
              const float* __restrict__ hour_e, const float* __restrict__ wk_e,
              const float* __restrict__ day_e, const float* __restrict__ mon_e,
              const float* __restrict__ W_val, const float* __restrict__ b_val,
              const float* __restrict__ b1, const float* __restrict__ b2,
              const float* __restrict__ b3, const float* __restrict__ gbi,
              const float* __restrict__ gbh, const float* __restrict__ fc_w,
              const float* __restrict__ fc_b, float* __restrict__ out) {
    __shared__ float abuf[4*ASUB];       // 42,240 B: subs = (batch bb, edge e)
    __shared__ float wbuf[16*GDIM];      // 24,576 B: conv/WiT chunks; later P+H
    __shared__ float gxe[NBB*12*GDIM];   // 36,864 B: edge gx rows per batch
    const int tid = threadIdx.x;
    const int b0 = blockIdx.x * NBB;

    // ---- phase 1: embedding, 4 subs x 20 rows
    for (int e = tid; e < 4*20*DM; e += 512) {
        int s = e / (20*DM);
        int rem = e - s*(20*DM);
        int q = rem >> 7, d = rem & 127;
        int wb = (s & 1) ? 83 : -6;
        int b = b0 + (s >> 1);
        int w = wb + q;
        float v = 0.f;
        if (w >= 0 && w < SEQ) {
            int p = i + w;
            const float* xr = (p < SEQ) ? (x_enc + (b*SEQ + p)*CIN)
                                        : (out + (b*PRED + (p - SEQ))*CIN);
            v = b_val[d];
            #pragma unroll
            for (int c = 0; c < CIN; ++c) v = fmaf(xr[c], W_val[d*CIN + c], v);
            const int* ym = y_mark + (b*TOT + p)*4;
            v += hour_e[ym[0]*DM + d] + wk_e[ym[1]*DM + d]
               + day_e[ym[2]*DM + d] + mon_e[ym[3]*DM + d];
        }
        abuf[s*ASUB + q*CSTR + d] = v;
    }
    // ---- phase 2: conv cascade (mlayer starts with __syncthreads)
    mlayer<2>(abuf, wbuf, g_wT,            b1, 16, 2, tid);  // c1: 4x16 rows
    mlayer<2>(abuf, wbuf, g_wT + W_CONV,   b2, 12, 4, tid);  // c2: 4x12 rows
    mlayer<1>(abuf, wbuf, g_wT + 2*W_CONV, b3,  8, 6, tid);  // c3: 4x8 rows

    // ---- phase 3: gx for 32 c3 rows; thread = 2 rows x 12 g
    {
        const int mp = tid >> 5;             // 0..15 row-pairs
        const int g0 = (tid & 31) * 12;
        const int s = mp >> 2;               // sub (2 rows same sub)
        const int row0 = (2*mp) & 7;
        const float* a0p = abuf + s*ASUB + row0*CSTR;
        const float* a1p = a0p + CSTR;
        const float* WiT = g_wT + OFF_WIT;
        float ga[2][12];
        #pragma unroll
        for (int e = 0; e < 12; ++e) { float bv = gbi[g0+e]; ga[0][e] = bv; ga[1][e] = bv; }
        for (int cc = 0; cc < 8; ++cc) {
            __syncthreads();
            for (int x = tid; x < 16*GDIM/4; x += 512)
                ((float4*)wbuf)[x] = ((const float4*)(WiT + cc*16*GDIM))[x];
            __syncthreads();
            #pragma unroll
            for (int c = 0; c < 16; ++c) {
                float av0 = a0p[cc*16 + c];
                float av1 = a1p[cc*16 + c];
                const float* wr = wbuf + c*GDIM + g0;
                #pragma unroll
                for (int q4 = 0; q4 < 3; ++q4) {
                    float4 w4 = *(const float4*)(wr + q4*4);
                    ga[0][q4*4+0] = fmaf(av0, w4.x, ga[0][q4*4+0]);
                    ga[0][q4*4+1] = fmaf(av0, w4.y, ga[0][q4*4+1]);
                    ga[0][q4*4+2] = fmaf(av0, w4.z, ga[0][q4*4+2]);
                    ga[0][q4*4+3] = fmaf(av0, w4.w, ga[0][q4*4+3]);
                    ga[1][q4*4+0] = fmaf(av1, w4.x, ga[1][q4*4+0]);
                    ga[1][q4*4+1] = fmaf(av1, w4.y, ga[1][q4*4+1]);
                    ga[1][q4*4+2] = fmaf(av1, w4.z, ga[1][q4*4+2]);
                    ga[1][q4*4+3] = fmaf(av1, w4.w, ga[1][q4*4+3]);
                }
            }
        }
        const int bb = s >> 1, edge = s & 1;
        const int b = b0 + bb;
        #pragma unroll
        for (int j = 0; j < 2; ++j) {
            int w = (edge ? 83 : -6) + 6 + row0 + j;
            float* dst = nullptr;
            if (edge == 0) {
                if (w < 6) dst = gxe + ((size_t)bb*12 + w)*GDIM + g0;
            } else {
                if (w == 89)      dst = g_gxg + ((size_t)b*TOT + (i + 89))*GDIM + g0;
                else if (w < SEQ) dst = gxe + ((size_t)bb*12 + (w - 84))*GDIM + g0;
            }
            if (dst) {
                *(float4*)(dst)     = *(const float4*)&ga[j][0];
                *(float4*)(dst + 4) = *(const float4*)&ga[j][4];
                *(float4*)(dst + 8) = *(const float4*)&ga[j][8];
            }
        }
    }
    __syncthreads();   // gxe + g_gxg(w=89) visible; wbuf free for P/H

    // ---- phase 4: GRU. thread = (unit j, c-slice s4); whr/whz/whn[32] = 96 floats.
    float* P = wbuf;                  // [3][4][NBB][DM] partials = 3072 floats
    float* H = wbuf + 3*4*NBB*DM;     // [2][NBB][DM] ping-pong hidden = 512 floats
    const int j = tid & 127, s4 = tid >> 7;
    float whr[32], whz[32], whn[32];
    {
        const float* Wp = g_wT + OFF_WHT + (size_t)(32*s4)*GDIM + j;
        #pragma unroll
        for (int c = 0; c < 32; ++c) {
            whr[c] = Wp[c*GDIM];
            whz[c] = Wp[c*GDIM + DM];
            whn[c] = Wp[c*GDIM + 2*DM];
        }
    }
    const bool comb = (tid < NBB*DM);
    const int cb = s4 & 1, cj = j;
    float bhr = 0.f, bhz = 0.f, bhn = 0.f, h = 0.f;
    float gxr = 0.f, gxz = 0.f, gxn = 0.f;
    if (comb) {
        bhr = gbh[cj]; bhz = gbh[DM + cj]; bhn = gbh[2*DM + cj];
        H[(0*NBB + cb)*DM + cj] = 0.f;
        gxr = gxe[(size_t)cb*12*GDIM + cj];
        gxz = gxe[(size_t)cb*12*GDIM + DM + cj];
        gxn = gxe[(size_t)cb*12*GDIM + 2*DM + cj];     // t = 0
    }
    __syncthreads();

    for (int t = 0; t < SEQ; ++t) {
        #pragma unroll
        for (int bb = 0; bb < NBB; ++bb) {
            const float* Hc = H + (((t & 1)*NBB) + bb)*DM + 32*s4;  // broadcast
            float ar = 0.f, az = 0.f, an = 0.f;
            #pragma unroll
            for (int c = 0; c < 32; c += 4) {
                float4 h4 = *(const float4*)(Hc + c);
                ar = fmaf(h4.x, whr[c],   ar); az = fmaf(h4.x, whz[c],   az); an = fmaf(h4.x, whn[c],   an);
                ar = fmaf(h4.y, whr[c+1], ar); az = fmaf(h4.y, whz[c+1], az); an = fmaf(h4.y, whn[c+1], an);
                ar = fmaf(h4.z, whr[c+2], ar); az = fmaf(h4.z, whz[c+2], az); an = fmaf(h4.z, whn[c+2], an);
                ar = fmaf(h4.w, whr[c+3], ar); az = fmaf(h4.w, whz[c+3], az); an = fmaf(h4.w, whn[c+3], an);
            }
            P[((0*4 + s4)*NBB + bb)*DM + j] = ar;
            P[((1*4 + s4)*NBB + bb)*DM + j] = az;
            P[((2*4 + s4)*NBB + bb)*DM + j] = an;
        }
        __syncthreads();
        if (comb) {
            float ar2 = bhr, az2 = bhz, an2 = bhn;
            #pragma unroll
            for (int ss = 0; ss < 4; ++ss) {
                ar2 += P[((0*4 + ss)*NBB + cb)*DM + cj];
                az2 += P[((1*4 + ss)*NBB + cb)*DM + cj];
                an2 += P[((2*4 + ss)*NBB + cb)*DM + cj];
            }
            float r = 1.f/(1.f + __expf(-(gxr + ar2)));
            float z = 1.f/(1.f + __expf(-(gxz + az2)));
            float xn = gxn + r*an2;
            float e2 = __expf(2.f*xn);
            float n = 1.f - 2.f/(e2 + 1.f);           // tanh(xn)
            h = (1.f - z)*n + z*h;
            H[(((t + 1) & 1)*NBB + cb)*DM + cj] = h;
            if (t + 1 < SEQ) {                        // prefetch next t's gx
                int t1 = t + 1;
                const float* gq = (t1 < 6)  ? (gxe + ((size_t)cb*12 + t1)*GDIM)
                                : (t1 < 90) ? (g_gxg + (((size_t)(b0 + cb)*TOT) + i + t1)*GDIM)
                                            : (gxe + ((size_t)cb*12 + (t1 - 84))*GDIM);
                gxr = gq[cj]; gxz = gq[DM + cj]; gxn = gq[2*DM + cj];
            }
        }
        __syncthreads();
    }

    // ---- FC: pred = h @ fc_w^T + fc_b (SEQ even -> final state at parity 0)
    if (tid < NBB*CIN) {
        int bb = tid / CIN, o = tid % CIN;
        float p = fc_b[o];
        const float* Hf = H + bb*DM;
        #pragma unroll
        for (int d = 0; d < DM; ++d) p = fmaf(fc_w[o*DM + d], Hf[d], p);
        out[((b0 + bb)*PRED + i)*CIN + o] = p;
    }
}

// ---------------------------------------------------------------- launch
extern "C" void kernel_launch(void* const* d_in, const int* in_sizes, int n_in,
                              void* d_out, int out_size, void* d_ws, size_t ws_size,
                              hipStream_t stream) {
    const float* x_enc  = (const float*)d_in[0];
    const int*   y_mark = (const int*)d_in[2];
    const float* hour_e = (const float*)d_in[3];
    const float* wk_e   = (const float*)d_in[4];
    const float* day_e  = (const float*)d_in[5];
    const float* mon_e  = (const float*)d_in[6];
    const float* W_val  = (const float*)d_in[7];
    const float* b_val  = (const float*)d_in[8];
    const float* c1w    = (const float*)d_in[9];
    const float* c1b    = (const float*)d_in[10];
    const float* c2w    = (const float*)d_in[11];
    const float* c2b    = (const float*)d_in[12];
    const float* c3w    = (const float*)d_in[13];
    const float* c3b    = (const float*)d_in[14];
    const float* Wi     = (const float*)d_in[15];
    const float* Wh     = (const float*)d_in[16];
    const float* gbi    = (const float*)d_in[17];
    const float* gbh    = (const float*)d_in[18];
    const float* fcw    = (const float*)d_in[19];
    const float* fcb    = (const float*)d_in[20];
    float* out = (float*)d_out;

    prep_weights<<<(W_TOTAL + 255)/256, 256, 0, stream>>>(c1w, c2w, c3w, Wi, Wh);

    init_kernel<<<dim3(B_SZ, 2), 256, 0, stream>>>(x_enc, y_mark,
        hour_e, wk_e, day_e, mon_e, W_val, b_val, c1b, c2b, c3b, gbi);

    for (int i = 0; i < PRED; ++i) {
        step_gru<<<B_SZ/NBB, 512, 0, stream>>>(i, x_enc, y_mark,
            hour_e, wk_e, day_e, mon_e, W_val, b_val, c1b, c2b, c3b,
            gbi, gbh, fcw, fcb, out);
    }
}